// Round 5
// baseline (395.001 us; speedup 1.0000x reference)
//
#include <hip/hip_runtime.h>
#include <math.h>

// GCN: atomic-free 2-level bucket-sort CSR build, then
// 3 x { h@W bf16-MFMA (*dinv epilogue) -> CSR-gather agg (bf16, MLP-4) -> +b -> LN -> ReLU } -> mean-pool
// N=50000, E=800000, D=128, G=64.  Requires N,src,dst < 65536 (edge packed as (dst<<16)|src).

#define NDIM 128
#define LN_EPS 1e-5f
#define NGRAPH 64
#define EPB 2048              // edges per histogram/scatter block

typedef __attribute__((ext_vector_type(8))) short short8;   // 8 bf16 = 4 VGPR (MFMA A/B frag)
typedef __attribute__((ext_vector_type(4))) float f32x4;    // MFMA C/D frag

__device__ __forceinline__ ushort f2bf(float f) {           // RNE fp32->bf16
    unsigned u = __float_as_uint(f);
    return (ushort)((u + 0x7FFF + ((u >> 16) & 1)) >> 16);
}
__device__ __forceinline__ float bf2f(ushort b) {
    return __uint_as_float(((unsigned)b) << 16);
}

// block-wide exclusive scan over 256 values (one per thread); s is 256-uint scratch
__device__ __forceinline__ uint block_excl_scan(uint v, uint* s) {
    int t = threadIdx.x;
    s[t] = v; __syncthreads();
    #pragma unroll
    for (int off = 1; off < 256; off <<= 1) {
        uint x = (t >= off) ? s[t - off] : 0u;
        __syncthreads();
        s[t] += x;
        __syncthreads();
    }
    uint incl = s[t];
    __syncthreads();            // safe scratch reuse
    return incl - v;
}

// ---------------- graph build (atomic-free bucket sort) ----------------

// Level-1 histogram: hist[b][j] = #edges in block b with dst>>8 == j
__global__ __launch_bounds__(256) void k_h1(const int* __restrict__ dst, uint* __restrict__ hist, int E) {
    __shared__ uint h[256];
    int t = threadIdx.x, b = blockIdx.x;
    h[t] = 0; __syncthreads();
    int e0 = b * EPB;
    #pragma unroll
    for (int i = 0; i < 8; i++) {
        int e = e0 + i * 256 + t;
        if (e < E) atomicAdd(&h[((uint)dst[e]) >> 8], 1u);
    }
    __syncthreads();
    hist[(size_t)b * 256 + t] = h[t];
}

// single block: column-scan hist into per-(block,bin) scatter offsets; emit bucket
// edge offsets (eoff, raw) and csr bucket bases (cbase, pad4 + per-node slack)
__global__ __launch_bounds__(256) void k_scan(uint* __restrict__ hist, uint* __restrict__ eoff,
                                              uint* __restrict__ cbase, int EB) {
    __shared__ uint s[256];
    int t = threadIdx.x;
    uint run = 0;
    for (int b = 0; b < EB; b++) {          // exclusive running count per column
        uint v = hist[(size_t)b * 256 + t];
        hist[(size_t)b * 256 + t] = run;
        run += v;
    }
    uint total = run;
    uint excl_raw = block_excl_scan(total, s);
    eoff[t] = excl_raw;
    if (t == 255) eoff[256] = excl_raw + total;     // == E
    uint excl_pad = block_excl_scan((total + 3u) & ~3u, s);
    cbase[t] = excl_pad + 768u * (uint)t;           // slack: <=3 pad per node * 256 nodes
    for (int b = 0; b < EB; b++)
        hist[(size_t)b * 256 + t] += excl_raw;      // absolute scatter offsets
}

// scatter edges into ebuf grouped by dst>>8, packed (dst<<16)|src; LDS ranks only
__global__ __launch_bounds__(256) void k_scatter1(const int* __restrict__ src, const int* __restrict__ dst,
                                                  const uint* __restrict__ hist, uint* __restrict__ ebuf, int E) {
    __shared__ uint off[256];
    __shared__ uint cur[256];
    int t = threadIdx.x, b = blockIdx.x;
    off[t] = hist[(size_t)b * 256 + t];
    cur[t] = 0;
    __syncthreads();
    int e0 = b * EPB;
    #pragma unroll
    for (int i = 0; i < 8; i++) {
        int e = e0 + i * 256 + t;
        if (e < E) {
            uint d = (uint)dst[e], sv = (uint)src[e];
            uint bin = d >> 8;
            uint r = atomicAdd(&cur[bin], 1u);
            ebuf[off[bin] + r] = (d << 16) | sv;
        }
    }
}

// one block per bucket (256 nodes): LDS sort by dst&255 -> csr (ushort src), deg/base/dinv,
// batch-boundary gstart/gend. Per-node bases padded to x4 (aligned ushort4 loads in k_agg).
__global__ __launch_bounds__(256) void k_sort2(const uint* __restrict__ ebuf, const uint* __restrict__ eoff,
                                               const uint* __restrict__ cbase, const int* __restrict__ batch,
                                               ushort* __restrict__ csr, int* __restrict__ base,
                                               int* __restrict__ deg, float* __restrict__ dinv,
                                               int* __restrict__ gstart, int* __restrict__ gend, int N) {
    __shared__ uint h[256], nbase[256], s[256];
    int t = threadIdx.x, b = blockIdx.x;
    uint lo = eoff[b];
    int cnt = (int)(eoff[b + 1] - lo);
    h[t] = 0; __syncthreads();
    for (int i = t; i < cnt; i += 256)
        atomicAdd(&h[(ebuf[lo + i] >> 16) & 255u], 1u);
    __syncthreads();
    uint dg = h[t];
    uint excl = block_excl_scan((dg + 3u) & ~3u, s);
    uint myb = cbase[b] + excl;
    nbase[t] = myb;
    int n = b * 256 + t;
    if (n < N) {
        base[n] = (int)myb;
        deg[n] = (int)dg;
        dinv[n] = rsqrtf((float)(dg + 1u));
        int g = batch[n];
        if (n == 0 || batch[n - 1] != g) gstart[g] = n;
        if (n == N - 1 || batch[n + 1] != g) gend[g] = n + 1;
    }
    h[t] = 0;                   // reuse as per-node cursor
    __syncthreads();
    for (int i = t; i < cnt; i += 256) {
        uint e = ebuf[lo + i];
        uint bin = (e >> 16) & 255u;
        uint r = atomicAdd(&h[bin], 1u);
        csr[nbase[bin] + r] = (ushort)(e & 0xFFFFu);
    }
}

// ---------------- weight prep: Wt[n][k] = W[k][n], bf16, XOR-swizzled in global ----------------

__global__ __launch_bounds__(256) void k_wt(const float* __restrict__ W, ushort* __restrict__ Wt) {
    int l = blockIdx.x;
    const float* w = W + (size_t)l * NDIM * NDIM;
    char* o = (char*)(Wt + (size_t)l * NDIM * NDIM);
    for (int idx = threadIdx.x; idx < NDIM * NDIM; idx += 256) {
        int k = idx >> 7, n = idx & 127;
        int byte = ((n * NDIM + k) * 2) ^ ((n & 7) << 4);
        *(ushort*)(o + byte) = f2bf(w[idx]);
    }
}

// ---------------- GEMM: C[N,128] = (A @ W) * dinv[row], bf16 MFMA ----------------

template <bool AF32>
__global__ __launch_bounds__(256) void k_gemm(const void* __restrict__ Ap, const ushort* __restrict__ Wt,
                                              ushort* __restrict__ C, const float* __restrict__ dinv, int N) {
    __shared__ char sW[32768];
    int tid = threadIdx.x;
    {   // stage pre-swizzled Wt (32KB) linearly
        const float4* g = (const float4*)Wt;
        float4* s = (float4*)sW;
        #pragma unroll
        for (int i = 0; i < 8; i++) s[tid + 256 * i] = g[tid + 256 * i];
    }
    __syncthreads();

    int wave = tid >> 6, lane = tid & 63;
    int l15 = lane & 15, lhi = lane >> 4;
    int row0 = blockIdx.x * 128 + wave * 32;

    f32x4 acc[2][8];
    #pragma unroll
    for (int m = 0; m < 2; m++)
        #pragma unroll
        for (int n = 0; n < 8; n++) acc[m][n] = f32x4{0.f, 0.f, 0.f, 0.f};

    const float*  Af = (const float*)Ap;
    const ushort* Ab = (const ushort*)Ap;

    #pragma unroll
    for (int ks = 0; ks < 4; ks++) {
        int k = ks * 32 + lhi * 8;
        short8 a[2];
        #pragma unroll
        for (int m = 0; m < 2; m++) {
            int r = row0 + m * 16 + l15;
            if (r < N) {
                if (AF32) {
                    float4 v0 = *(const float4*)&Af[(size_t)r * NDIM + k];
                    float4 v1 = *(const float4*)&Af[(size_t)r * NDIM + k + 4];
                    short8 t;
                    t[0] = (short)f2bf(v0.x); t[1] = (short)f2bf(v0.y);
                    t[2] = (short)f2bf(v0.z); t[3] = (short)f2bf(v0.w);
                    t[4] = (short)f2bf(v1.x); t[5] = (short)f2bf(v1.y);
                    t[6] = (short)f2bf(v1.z); t[7] = (short)f2bf(v1.w);
                    a[m] = t;
                } else {
                    a[m] = *(const short8*)&Ab[(size_t)r * NDIM + k];
                }
            } else {
                a[m] = short8{};
            }
        }
        #pragma unroll
        for (int n = 0; n < 8; n++) {
            int nn = n * 16 + l15;
            int byte = (nn * 256 + k * 2) ^ ((nn & 7) << 4);
            short8 b = *(const short8*)(sW + byte);
            acc[0][n] = __builtin_amdgcn_mfma_f32_16x16x32_bf16(a[0], b, acc[0][n], 0, 0, 0);
            acc[1][n] = __builtin_amdgcn_mfma_f32_16x16x32_bf16(a[1], b, acc[1][n], 0, 0, 0);
        }
    }

    #pragma unroll
    for (int m = 0; m < 2; m++) {
        int rbase = row0 + m * 16 + lhi * 4;
        #pragma unroll
        for (int r = 0; r < 4; r++) {
            int row = rbase + r;
            if (row < N) {
                float dn = dinv[row];
                #pragma unroll
                for (int n = 0; n < 8; n++)
                    C[(size_t)row * NDIM + n * 16 + l15] = f2bf(acc[m][n][r] * dn);
            }
        }
    }
}

// ---------------- fused aggregate + bias + LayerNorm + ReLU (bf16 in/out) ----------------
// half-wave (32 lanes) per node; lane owns 4 dims. Unroll-4 gather with ushort4 index prefetch.

__global__ __launch_bounds__(256) void k_agg(const ushort* __restrict__ hw, ushort* __restrict__ out,
                                             const float* __restrict__ dinv, const int* __restrict__ base,
                                             const int* __restrict__ deg, const ushort* __restrict__ csr,
                                             const float* __restrict__ bias, const float* __restrict__ gamma,
                                             const float* __restrict__ beta, int N) {
    int gtid = blockIdx.x * 256 + threadIdx.x;
    int n = gtid >> 5;
    int l4 = threadIdx.x & 31;
    if (n >= N) return;

    const ushort4* hv = (const ushort4*)hw;
    ushort4 sv = hv[(size_t)n * 32 + l4];            // self term (pre-scaled by dinv)
    float a0 = bf2f(sv.x), a1 = bf2f(sv.y), a2 = bf2f(sv.z), a3 = bf2f(sv.w);

    int b0 = base[n], dg = deg[n];
    int nfull = dg & ~3;
    ushort4 s4;
    if (nfull > 0) s4 = *(const ushort4*)&csr[b0];   // base padded to x4 -> 8B aligned
    for (int i = 0; i < nfull; i += 4) {
        ushort4 cur = s4;
        if (i + 4 < nfull) s4 = *(const ushort4*)&csr[b0 + i + 4];
        ushort4 t0 = hv[(size_t)cur.x * 32 + l4];
        ushort4 t1 = hv[(size_t)cur.y * 32 + l4];
        ushort4 t2 = hv[(size_t)cur.z * 32 + l4];
        ushort4 t3 = hv[(size_t)cur.w * 32 + l4];
        a0 += bf2f(t0.x) + bf2f(t1.x) + bf2f(t2.x) + bf2f(t3.x);
        a1 += bf2f(t0.y) + bf2f(t1.y) + bf2f(t2.y) + bf2f(t3.y);
        a2 += bf2f(t0.z) + bf2f(t1.z) + bf2f(t2.z) + bf2f(t3.z);
        a3 += bf2f(t0.w) + bf2f(t1.w) + bf2f(t2.w) + bf2f(t3.w);
    }
    for (int i = nfull; i < dg; i++) {
        int s = csr[b0 + i];
        ushort4 t = hv[(size_t)s * 32 + l4];
        a0 += bf2f(t.x); a1 += bf2f(t.y); a2 += bf2f(t.z); a3 += bf2f(t.w);
    }

    float dn = dinv[n];
    a0 *= dn; a1 *= dn; a2 *= dn; a3 *= dn;

    float4 bv = ((const float4*)bias)[l4];
    a0 += bv.x; a1 += bv.y; a2 += bv.z; a3 += bv.w;

    float s1 = a0 + a1 + a2 + a3;
    float s2 = a0 * a0 + a1 * a1 + a2 * a2 + a3 * a3;
    #pragma unroll
    for (int o = 1; o < 32; o <<= 1) {
        s1 += __shfl_xor(s1, o);
        s2 += __shfl_xor(s2, o);
    }
    float mu = s1 * (1.f / NDIM);
    float var = s2 * (1.f / NDIM) - mu * mu;
    float rs = rsqrtf(var + LN_EPS);

    float4 gv = ((const float4*)gamma)[l4];
    float4 be = ((const float4*)beta)[l4];
    ushort4 y;
    y.x = f2bf(fmaxf(gv.x * (a0 - mu) * rs + be.x, 0.f));
    y.y = f2bf(fmaxf(gv.y * (a1 - mu) * rs + be.y, 0.f));
    y.z = f2bf(fmaxf(gv.z * (a2 - mu) * rs + be.z, 0.f));
    y.w = f2bf(fmaxf(gv.w * (a3 - mu) * rs + be.w, 0.f));
    ((ushort4*)out)[(size_t)n * 32 + l4] = y;
}

// ---------------- mean pool (bf16 in, fp32 out) ----------------

__global__ __launch_bounds__(128) void k_pool(const ushort* __restrict__ h, const int* __restrict__ batch,
                                              float* __restrict__ out, int N) {
    int d = threadIdx.x;
    int start = blockIdx.x * 64;
    if (start >= N) return;
    int end = min(start + 64, N);
    int cur = batch[start];
    float sum = 0.f;
    for (int n = start; n < end; n++) {
        int g = batch[n];
        if (g != cur) {
            atomicAdd(&out[cur * NDIM + d], sum);
            sum = 0.f;
            cur = g;
        }
        sum += bf2f(h[(size_t)n * NDIM + d]);
    }
    atomicAdd(&out[cur * NDIM + d], sum);
}

__global__ __launch_bounds__(256) void k_div(float* __restrict__ out, const int* __restrict__ gstart,
                                             const int* __restrict__ gend) {
    int i = blockIdx.x * 256 + threadIdx.x;
    if (i < NGRAPH * NDIM) {
        int g = i >> 7;
        float c = (float)(gend[g] - gstart[g]);
        out[i] /= fmaxf(c, 1.f);
    }
}

// ---------------- launch ----------------

extern "C" void kernel_launch(void* const* d_in, const int* in_sizes, int n_in,
                              void* d_out, int out_size, void* d_ws, size_t ws_size,
                              hipStream_t stream) {
    const float* x      = (const float*)d_in[0];
    const int*   ei     = (const int*)d_in[1];
    const int*   batch  = (const int*)d_in[2];
    const float* Ws     = (const float*)d_in[3];
    const float* bs     = (const float*)d_in[4];
    const float* gammas = (const float*)d_in[5];
    const float* betas  = (const float*)d_in[6];
    float* out = (float*)d_out;

    int N = in_sizes[0] / NDIM;
    int E = in_sizes[1] / 2;
    const int* src = ei;
    const int* dst = ei + E;
    int EB = (E + EPB - 1) / EPB;       // 391 histogram/scatter blocks
    int NB = (N + 255) / 256;           // 196 buckets (requires N <= 65536)

    char* w = (char*)d_ws;
    auto alloc = [&](size_t bytes) { char* p = w; w += (bytes + 255) & ~(size_t)255; return p; };
    int*    deg    = (int*)alloc((size_t)N * 4);
    int*    base   = (int*)alloc((size_t)N * 4);
    float*  dinv   = (float*)alloc((size_t)N * 4);
    uint*   hist   = (uint*)alloc((size_t)EB * 256 * 4);
    uint*   eoff   = (uint*)alloc(257 * 4);
    uint*   cbase  = (uint*)alloc(256 * 4);
    uint*   ebuf   = (uint*)alloc((size_t)E * 4);
    ushort* csr    = (ushort*)alloc(((size_t)E + 256u * 772u) * 2);   // pad4-per-node + bucket slack
    int*    gse    = (int*)alloc(2 * NGRAPH * 4);
    int*    gstart = gse;
    int*    gend   = gse + NGRAPH;
    ushort* Wt     = (ushort*)alloc((size_t)3 * NDIM * NDIM * 2);
    ushort* bufA   = (ushort*)alloc((size_t)N * NDIM * 2);   // h (bf16)
    ushort* bufB   = (ushort*)alloc((size_t)N * NDIM * 2);   // hw (bf16)

    hipMemsetAsync(out, 0, (size_t)NGRAPH * NDIM * 4, stream);

    k_h1<<<EB, 256, 0, stream>>>(dst, hist, E);
    k_scan<<<1, 256, 0, stream>>>(hist, eoff, cbase, EB);
    k_scatter1<<<EB, 256, 0, stream>>>(src, dst, hist, ebuf, E);
    k_sort2<<<NB, 256, 0, stream>>>(ebuf, eoff, cbase, batch, csr, base, deg, dinv, gstart, gend, N);
    k_wt<<<3, 256, 0, stream>>>(Ws, Wt);

    int gGemm = (N + 127) / 128;
    int gAgg  = (N * 32 + 255) / 256;
    for (int l = 0; l < 3; l++) {
        const ushort* wl = Wt + (size_t)l * NDIM * NDIM;
        if (l == 0)
            k_gemm<true><<<gGemm, 256, 0, stream>>>((const void*)x, wl, bufB, dinv, N);
        else
            k_gemm<false><<<gGemm, 256, 0, stream>>>((const void*)bufA, wl, bufB, dinv, N);
        k_agg<<<gAgg, 256, 0, stream>>>(bufB, bufA, dinv, base, deg, csr,
                                        bs + l * NDIM, gammas + l * NDIM, betas + l * NDIM, N);
    }

    k_pool<<<(N + 63) / 64, 128, 0, stream>>>(bufA, batch, out, N);
    k_div<<<(NGRAPH * NDIM + 255) / 256, 256, 0, stream>>>(out, gstart, gend);
}

// Round 7
// 283.221 us; speedup vs baseline: 1.3947x; 1.3947x over previous
//
#include <hip/hip_runtime.h>
#include <math.h>

// GCN: atomic-free 2-level bucket-sort CSR build (parallel hierarchical scan), then
// 3 x { h@W bf16-MFMA (*dinv epilogue) -> CSR-gather agg (bf16, MLP-4) -> +b -> LN -> ReLU } -> mean-pool
// N=50000, E=800000, D=128, G=64.  Requires N,src,dst < 65536 and E <= 512*EPB.

#define NDIM 128
#define LN_EPS 1e-5f
#define NGRAPH 64
#define EPB 2048              // edges per histogram/scatter block

typedef __attribute__((ext_vector_type(8))) short short8;   // 8 bf16 = 4 VGPR (MFMA A/B frag)
typedef __attribute__((ext_vector_type(4))) float f32x4;    // MFMA C/D frag

__device__ __forceinline__ ushort f2bf(float f) {           // RNE fp32->bf16
    unsigned u = __float_as_uint(f);
    return (ushort)((u + 0x7FFF + ((u >> 16) & 1)) >> 16);
}
__device__ __forceinline__ float bf2f(ushort b) {
    return __uint_as_float(((unsigned)b) << 16);
}

// block-wide exclusive scan over 256 values (one per thread); s is 256-uint scratch
__device__ __forceinline__ uint block_excl_scan(uint v, uint* s) {
    int t = threadIdx.x;
    s[t] = v; __syncthreads();
    #pragma unroll
    for (int off = 1; off < 256; off <<= 1) {
        uint x = (t >= off) ? s[t - off] : 0u;
        __syncthreads();
        s[t] += x;
        __syncthreads();
    }
    uint incl = s[t];
    __syncthreads();            // safe scratch reuse
    return incl - v;
}

// ---------------- graph build (atomic-free bucket sort) ----------------

// Level-1 histogram: hist[b][j] = #edges in block b with dst>>8 == j
__global__ __launch_bounds__(256) void k_h1(const int* __restrict__ dst, uint* __restrict__ hist, int E) {
    __shared__ uint h[256];
    int t = threadIdx.x, b = blockIdx.x;
    h[t] = 0; __syncthreads();
    int e0 = b * EPB;
    #pragma unroll
    for (int i = 0; i < 8; i++) {
        int e = e0 + i * 256 + t;
        if (e < E) atomicAdd(&h[((uint)dst[e]) >> 8], 1u);
    }
    __syncthreads();
    hist[(size_t)b * 256 + t] = h[t];
}

// one block per bin: exclusive scan down the column (2 rows/thread, EB<=512),
// leaves within-column exclusive prefixes in hist, column total in colsum
__global__ __launch_bounds__(256) void k_colscan(uint* __restrict__ hist, uint* __restrict__ colsum, int EB) {
    __shared__ uint s[256];
    int t = threadIdx.x, j = blockIdx.x;
    uint v0 = (2 * t     < EB) ? hist[(size_t)(2 * t) * 256 + j] : 0u;
    uint v1 = (2 * t + 1 < EB) ? hist[(size_t)(2 * t + 1) * 256 + j] : 0u;
    uint pair = v0 + v1;
    uint excl = block_excl_scan(pair, s);
    if (2 * t < EB)     hist[(size_t)(2 * t) * 256 + j] = excl;
    if (2 * t + 1 < EB) hist[(size_t)(2 * t + 1) * 256 + j] = excl + v0;
    if (t == 255) colsum[j] = excl + pair;
}

// single small block: scan the 256 column totals -> bucket edge offsets (eoff, raw)
// and csr bucket bases (cbase, pad4 + per-node slack)
__global__ __launch_bounds__(256) void k_binscan(const uint* __restrict__ colsum, uint* __restrict__ eoff,
                                                 uint* __restrict__ cbase) {
    __shared__ uint s[256];
    int t = threadIdx.x;
    uint total = colsum[t];
    uint er = block_excl_scan(total, s);
    eoff[t] = er;
    if (t == 255) eoff[256] = er + total;           // == E
    uint ep = block_excl_scan((total + 3u) & ~3u, s);
    cbase[t] = ep + 768u * (uint)t;                 // slack: <=3 pad per node * 256 nodes
}

// scatter edges into ebuf grouped by dst>>8, packed (dst<<16)|src; LDS ranks only
__global__ __launch_bounds__(256) void k_scatter1(const int* __restrict__ src, const int* __restrict__ dst,
                                                  const uint* __restrict__ hist, const uint* __restrict__ eoff,
                                                  uint* __restrict__ ebuf, int E) {
    __shared__ uint off[256];
    __shared__ uint cur[256];
    int t = threadIdx.x, b = blockIdx.x;
    off[t] = eoff[t] + hist[(size_t)b * 256 + t];
    cur[t] = 0;
    __syncthreads();
    int e0 = b * EPB;
    #pragma unroll
    for (int i = 0; i < 8; i++) {
        int e = e0 + i * 256 + t;
        if (e < E) {
            uint d = (uint)dst[e], sv = (uint)src[e];
            uint bin = d >> 8;
            uint r = atomicAdd(&cur[bin], 1u);
            ebuf[off[bin] + r] = (d << 16) | sv;
        }
    }
}

// one block per bucket (256 nodes): LDS sort by dst&255 -> csr (ushort src), deg/base/dinv,
// batch-boundary gstart/gend. Per-node bases padded to x4 (aligned ushort4 loads in k_agg).
__global__ __launch_bounds__(256) void k_sort2(const uint* __restrict__ ebuf, const uint* __restrict__ eoff,
                                               const uint* __restrict__ cbase, const int* __restrict__ batch,
                                               ushort* __restrict__ csr, int* __restrict__ base,
                                               int* __restrict__ deg, float* __restrict__ dinv,
                                               int* __restrict__ gstart, int* __restrict__ gend, int N) {
    __shared__ uint h[256], nbase[256], s[256];
    int t = threadIdx.x, b = blockIdx.x;
    uint lo = eoff[b];
    int cnt = (int)(eoff[b + 1] - lo);
    h[t] = 0; __syncthreads();
    for (int i = t; i < cnt; i += 256)
        atomicAdd(&h[(ebuf[lo + i] >> 16) & 255u], 1u);
    __syncthreads();
    uint dg = h[t];
    uint excl = block_excl_scan((dg + 3u) & ~3u, s);
    uint myb = cbase[b] + excl;
    nbase[t] = myb;
    int n = b * 256 + t;
    if (n < N) {
        base[n] = (int)myb;
        deg[n] = (int)dg;
        dinv[n] = rsqrtf((float)(dg + 1u));
        int g = batch[n];
        if (n == 0 || batch[n - 1] != g) gstart[g] = n;
        if (n == N - 1 || batch[n + 1] != g) gend[g] = n + 1;
    }
    h[t] = 0;                   // reuse as per-node cursor
    __syncthreads();
    for (int i = t; i < cnt; i += 256) {
        uint e = ebuf[lo + i];
        uint bin = (e >> 16) & 255u;
        uint r = atomicAdd(&h[bin], 1u);
        csr[nbase[bin] + r] = (ushort)(e & 0xFFFFu);
    }
}

// ---------------- weight prep: Wt[n][k] = W[k][n], bf16, XOR-swizzled in global ----------------

__global__ __launch_bounds__(256) void k_wt(const float* __restrict__ W, ushort* __restrict__ Wt) {
    int l = blockIdx.x;
    const float* w = W + (size_t)l * NDIM * NDIM;
    char* o = (char*)(Wt + (size_t)l * NDIM * NDIM);
    for (int idx = threadIdx.x; idx < NDIM * NDIM; idx += 256) {
        int k = idx >> 7, n = idx & 127;
        int byte = ((n * NDIM + k) * 2) ^ ((n & 7) << 4);
        *(ushort*)(o + byte) = f2bf(w[idx]);
    }
}

// ---------------- GEMM: C[N,128] = (A @ W) * dinv[row], bf16 MFMA ----------------

template <bool AF32>
__global__ __launch_bounds__(256) void k_gemm(const void* __restrict__ Ap, const ushort* __restrict__ Wt,
                                              ushort* __restrict__ C, const float* __restrict__ dinv, int N) {
    __shared__ char sW[32768];
    int tid = threadIdx.x;
    {   // stage pre-swizzled Wt (32KB) linearly
        const float4* g = (const float4*)Wt;
        float4* s = (float4*)sW;
        #pragma unroll
        for (int i = 0; i < 8; i++) s[tid + 256 * i] = g[tid + 256 * i];
    }
    __syncthreads();

    int wave = tid >> 6, lane = tid & 63;
    int l15 = lane & 15, lhi = lane >> 4;
    int row0 = blockIdx.x * 128 + wave * 32;

    f32x4 acc[2][8];
    #pragma unroll
    for (int m = 0; m < 2; m++)
        #pragma unroll
        for (int n = 0; n < 8; n++) acc[m][n] = f32x4{0.f, 0.f, 0.f, 0.f};

    const float*  Af = (const float*)Ap;
    const ushort* Ab = (const ushort*)Ap;

    #pragma unroll
    for (int ks = 0; ks < 4; ks++) {
        int k = ks * 32 + lhi * 8;
        short8 a[2];
        #pragma unroll
        for (int m = 0; m < 2; m++) {
            int r = row0 + m * 16 + l15;
            if (r < N) {
                if (AF32) {
                    float4 v0 = *(const float4*)&Af[(size_t)r * NDIM + k];
                    float4 v1 = *(const float4*)&Af[(size_t)r * NDIM + k + 4];
                    short8 t;
                    t[0] = (short)f2bf(v0.x); t[1] = (short)f2bf(v0.y);
                    t[2] = (short)f2bf(v0.z); t[3] = (short)f2bf(v0.w);
                    t[4] = (short)f2bf(v1.x); t[5] = (short)f2bf(v1.y);
                    t[6] = (short)f2bf(v1.z); t[7] = (short)f2bf(v1.w);
                    a[m] = t;
                } else {
                    a[m] = *(const short8*)&Ab[(size_t)r * NDIM + k];
                }
            } else {
                a[m] = short8{};
            }
        }
        #pragma unroll
        for (int n = 0; n < 8; n++) {
            int nn = n * 16 + l15;
            int byte = (nn * 256 + k * 2) ^ ((nn & 7) << 4);
            short8 b = *(const short8*)(sW + byte);
            acc[0][n] = __builtin_amdgcn_mfma_f32_16x16x32_bf16(a[0], b, acc[0][n], 0, 0, 0);
            acc[1][n] = __builtin_amdgcn_mfma_f32_16x16x32_bf16(a[1], b, acc[1][n], 0, 0, 0);
        }
    }

    #pragma unroll
    for (int m = 0; m < 2; m++) {
        int rbase = row0 + m * 16 + lhi * 4;
        #pragma unroll
        for (int r = 0; r < 4; r++) {
            int row = rbase + r;
            if (row < N) {
                float dn = dinv[row];
                #pragma unroll
                for (int n = 0; n < 8; n++)
                    C[(size_t)row * NDIM + n * 16 + l15] = f2bf(acc[m][n][r] * dn);
            }
        }
    }
}

// ---------------- fused aggregate + bias + LayerNorm + ReLU (bf16 in/out) ----------------
// half-wave (32 lanes) per node; lane owns 4 dims. Unroll-4 gather with ushort4 index prefetch.

__global__ __launch_bounds__(256) void k_agg(const ushort* __restrict__ hw, ushort* __restrict__ out,
                                             const float* __restrict__ dinv, const int* __restrict__ base,
                                             const int* __restrict__ deg, const ushort* __restrict__ csr,
                                             const float* __restrict__ bias, const float* __restrict__ gamma,
                                             const float* __restrict__ beta, int N) {
    int gtid = blockIdx.x * 256 + threadIdx.x;
    int n = gtid >> 5;
    int l4 = threadIdx.x & 31;
    if (n >= N) return;

    const ushort4* hv = (const ushort4*)hw;
    ushort4 sv = hv[(size_t)n * 32 + l4];            // self term (pre-scaled by dinv)
    float a0 = bf2f(sv.x), a1 = bf2f(sv.y), a2 = bf2f(sv.z), a3 = bf2f(sv.w);

    int b0 = base[n], dg = deg[n];
    int nfull = dg & ~3;
    ushort4 s4;
    if (nfull > 0) s4 = *(const ushort4*)&csr[b0];   // base padded to x4 -> 8B aligned
    for (int i = 0; i < nfull; i += 4) {
        ushort4 cur = s4;
        if (i + 4 < nfull) s4 = *(const ushort4*)&csr[b0 + i + 4];
        ushort4 t0 = hv[(size_t)cur.x * 32 + l4];
        ushort4 t1 = hv[(size_t)cur.y * 32 + l4];
        ushort4 t2 = hv[(size_t)cur.z * 32 + l4];
        ushort4 t3 = hv[(size_t)cur.w * 32 + l4];
        a0 += bf2f(t0.x) + bf2f(t1.x) + bf2f(t2.x) + bf2f(t3.x);
        a1 += bf2f(t0.y) + bf2f(t1.y) + bf2f(t2.y) + bf2f(t3.y);
        a2 += bf2f(t0.z) + bf2f(t1.z) + bf2f(t2.z) + bf2f(t3.z);
        a3 += bf2f(t0.w) + bf2f(t1.w) + bf2f(t2.w) + bf2f(t3.w);
    }
    for (int i = nfull; i < dg; i++) {
        int s = csr[b0 + i];
        ushort4 t = hv[(size_t)s * 32 + l4];
        a0 += bf2f(t.x); a1 += bf2f(t.y); a2 += bf2f(t.z); a3 += bf2f(t.w);
    }

    float dn = dinv[n];
    a0 *= dn; a1 *= dn; a2 *= dn; a3 *= dn;

    float4 bv = ((const float4*)bias)[l4];
    a0 += bv.x; a1 += bv.y; a2 += bv.z; a3 += bv.w;

    float s1 = a0 + a1 + a2 + a3;
    float s2 = a0 * a0 + a1 * a1 + a2 * a2 + a3 * a3;
    #pragma unroll
    for (int o = 1; o < 32; o <<= 1) {
        s1 += __shfl_xor(s1, o);
        s2 += __shfl_xor(s2, o);
    }
    float mu = s1 * (1.f / NDIM);
    float var = s2 * (1.f / NDIM) - mu * mu;
    float rs = rsqrtf(var + LN_EPS);

    float4 gv = ((const float4*)gamma)[l4];
    float4 be = ((const float4*)beta)[l4];
    ushort4 y;
    y.x = f2bf(fmaxf(gv.x * (a0 - mu) * rs + be.x, 0.f));
    y.y = f2bf(fmaxf(gv.y * (a1 - mu) * rs + be.y, 0.f));
    y.z = f2bf(fmaxf(gv.z * (a2 - mu) * rs + be.z, 0.f));
    y.w = f2bf(fmaxf(gv.w * (a3 - mu) * rs + be.w, 0.f));
    ((ushort4*)out)[(size_t)n * 32 + l4] = y;
}

// ---------------- mean pool (bf16 in, fp32 out) ----------------

__global__ __launch_bounds__(128) void k_pool(const ushort* __restrict__ h, const int* __restrict__ batch,
                                              float* __restrict__ out, int N) {
    int d = threadIdx.x;
    int start = blockIdx.x * 64;
    if (start >= N) return;
    int end = min(start + 64, N);
    int cur = batch[start];
    float sum = 0.f;
    for (int n = start; n < end; n++) {
        int g = batch[n];
        if (g != cur) {
            atomicAdd(&out[cur * NDIM + d], sum);
            sum = 0.f;
            cur = g;
        }
        sum += bf2f(h[(size_t)n * NDIM + d]);
    }
    atomicAdd(&out[cur * NDIM + d], sum);
}

__global__ __launch_bounds__(256) void k_div(float* __restrict__ out, const int* __restrict__ gstart,
                                             const int* __restrict__ gend) {
    int i = blockIdx.x * 256 + threadIdx.x;
    if (i < NGRAPH * NDIM) {
        int g = i >> 7;
        float c = (float)(gend[g] - gstart[g]);
        out[i] /= fmaxf(c, 1.f);
    }
}

// ---------------- launch ----------------

extern "C" void kernel_launch(void* const* d_in, const int* in_sizes, int n_in,
                              void* d_out, int out_size, void* d_ws, size_t ws_size,
                              hipStream_t stream) {
    const float* x      = (const float*)d_in[0];
    const int*   ei     = (const int*)d_in[1];
    const int*   batch  = (const int*)d_in[2];
    const float* Ws     = (const float*)d_in[3];
    const float* bs     = (const float*)d_in[4];
    const float* gammas = (const float*)d_in[5];
    const float* betas  = (const float*)d_in[6];
    float* out = (float*)d_out;

    int N = in_sizes[0] / NDIM;
    int E = in_sizes[1] / 2;
    const int* src = ei;
    const int* dst = ei + E;
    int EB = (E + EPB - 1) / EPB;       // 391 blocks (must be <= 512 for k_colscan)
    int NB = (N + 255) / 256;           // 196 buckets (requires N <= 65536)

    char* w = (char*)d_ws;
    auto alloc = [&](size_t bytes) { char* p = w; w += (bytes + 255) & ~(size_t)255; return p; };
    int*    deg    = (int*)alloc((size_t)N * 4);
    int*    base   = (int*)alloc((size_t)N * 4);
    float*  dinv   = (float*)alloc((size_t)N * 4);
    uint*   hist   = (uint*)alloc((size_t)EB * 256 * 4);
    uint*   colsum = (uint*)alloc(256 * 4);
    uint*   eoff   = (uint*)alloc(257 * 4);
    uint*   cbase  = (uint*)alloc(256 * 4);
    uint*   ebuf   = (uint*)alloc((size_t)E * 4);
    ushort* csr    = (ushort*)alloc(((size_t)E + 256u * 772u) * 2);   // pad4-per-node + bucket slack
    int*    gse    = (int*)alloc(2 * NGRAPH * 4);
    int*    gstart = gse;
    int*    gend   = gse + NGRAPH;
    ushort* Wt     = (ushort*)alloc((size_t)3 * NDIM * NDIM * 2);
    ushort* bufA   = (ushort*)alloc((size_t)N * NDIM * 2);   // h (bf16)
    ushort* bufB   = (ushort*)alloc((size_t)N * NDIM * 2);   // hw (bf16)

    hipMemsetAsync(out, 0, (size_t)NGRAPH * NDIM * 4, stream);

    k_h1<<<EB, 256, 0, stream>>>(dst, hist, E);
    k_colscan<<<256, 256, 0, stream>>>(hist, colsum, EB);
    k_binscan<<<1, 256, 0, stream>>>(colsum, eoff, cbase);
    k_scatter1<<<EB, 256, 0, stream>>>(src, dst, hist, eoff, ebuf, E);
    k_sort2<<<NB, 256, 0, stream>>>(ebuf, eoff, cbase, batch, csr, base, deg, dinv, gstart, gend, N);
    k_wt<<<3, 256, 0, stream>>>(Ws, Wt);

    int gGemm = (N + 127) / 128;
    int gAgg  = (N * 32 + 255) / 256;
    for (int l = 0; l < 3; l++) {
        const ushort* wl = Wt + (size_t)l * NDIM * NDIM;
        if (l == 0)
            k_gemm<true><<<gGemm, 256, 0, stream>>>((const void*)x, wl, bufB, dinv, N);
        else
            k_gemm<false><<<gGemm, 256, 0, stream>>>((const void*)bufA, wl, bufB, dinv, N);
        k_agg<<<gAgg, 256, 0, stream>>>(bufB, bufA, dinv, base, deg, csr,
                                        bs + l * NDIM, gammas + l * NDIM, betas + l * NDIM, N);
    }

    k_pool<<<(N + 63) / 64, 128, 0, stream>>>(bufA, batch, out, N);
    k_div<<<(NGRAPH * NDIM + 255) / 256, 256, 0, stream>>>(out, gstart, gend);
}